// Round 7
// baseline (236.301 us; speedup 1.0000x reference)
//
#include <hip/hip_runtime.h>

#define BATCH 65536
#define MT 128                // rows per block (2 panels of 64)
#define NBLK (BATCH / MT)     // 512

typedef unsigned short u16;
typedef __bf16 bf16x8 __attribute__((ext_vector_type(8)));
typedef float f32x4 __attribute__((ext_vector_type(4)));

// d_ws layout (u16 element offsets) — fragment-native weight layouts:
//   W'[K32][col][g][e]: element (col, k) at [K32][col][k>>3 & 3][k&7], k = K32*32+g*8+e
#define WI_OFF 0              // [1][512][4][8]   (k>=16 zero)
#define WH_OFF 16384          // [2][16][512][4][8]
#define WO_OFF 540672         // [16][32][4][8]   (cols o padded 17->32)
#define WS_USH 557056
// float region at (char*)ws + WS_USH*2
#define BI_F 0
#define BH_F 512
#define BO_F 1536
#define PART_F 1568           // [NBLK][2] per-block error partials
#define PREP_WH 65536
#define PREP_WI 2048
#define PREP_WO 2048
#define PREP_SC 1568
#define PREP_TOTAL (PREP_WH + PREP_WI + PREP_WO + PREP_SC)

__device__ inline u16 f2bf(float f) {
  union { float f; unsigned u; } v; v.f = f;
  unsigned u = v.u + 0x7fffu + ((v.u >> 16) & 1u);   // RNE
  return (u16)(u >> 16);
}

__global__ void prep_kernel(const float* __restrict__ w_in, const float* __restrict__ b_in,
                            const float* __restrict__ w_hid, const float* __restrict__ b_hid,
                            const float* __restrict__ w_out, const float* __restrict__ b_out,
                            const int* __restrict__ variant, int n,
                            u16* __restrict__ wsu, float* __restrict__ wsf)
{
  const int model = (n - 5) * 16 + variant[0];
  const int i = blockIdx.x * 256 + threadIdx.x;
  if (i < PREP_WH) {
    int g = i & 3, col = (i >> 2) & 511, K32 = (i >> 11) & 15, l = i >> 15;
    const float* src = w_hid + (size_t)model * 524288 + (size_t)l * 262144 + col * 512 + K32 * 32 + g * 8;
    u16* dst = wsu + WH_OFF + (size_t)i * 8;
    #pragma unroll
    for (int e = 0; e < 8; ++e) dst[e] = f2bf(src[e]);
  } else if (i < PREP_WH + PREP_WI) {
    int j = i - PREP_WH;
    int g = j & 3, col = j >> 2;
    u16* dst = wsu + WI_OFF + (size_t)j * 8;
    #pragma unroll
    for (int e = 0; e < 8; ++e) {
      int k = g * 8 + e;
      dst[e] = (k < 16) ? f2bf(w_in[(size_t)model * 8192 + col * 16 + k]) : (u16)0;
    }
  } else if (i < PREP_WH + PREP_WI + PREP_WO) {
    int j = i - PREP_WH - PREP_WI;
    int g = j & 3, col = (j >> 2) & 31, K32 = j >> 7;
    u16* dst = wsu + WO_OFF + (size_t)j * 8;
    #pragma unroll
    for (int e = 0; e < 8; ++e) {
      int k = K32 * 32 + g * 8 + e;
      dst[e] = (col < 17) ? f2bf(w_out[(size_t)model * 8704 + col * 512 + k]) : (u16)0;
    }
  } else if (i < PREP_TOTAL) {
    int j = i - PREP_WH - PREP_WI - PREP_WO;
    if (j < 512)       wsf[BI_F + j] = b_in[(size_t)model * 512 + j];
    else if (j < 1536) wsf[BH_F + (j - 512)] = b_hid[(size_t)model * 1024 + (j - 512)];
    else               { int o = j - 1536; wsf[BO_F + o] = (o < 17) ? b_out[(size_t)model * 17 + o] : 0.f; }
  }
}

// xs layout: byte = row*1024 + ((col*2) ^ ((row&15)<<4))
__device__ __forceinline__ bf16x8 rdA(const char* xb, int row, int kbyte) {
  return *reinterpret_cast<const bf16x8*>(xb + row * 1024 + (kbyte ^ ((row & 15) << 4)));
}
__device__ __forceinline__ void st16(char* xb, int row, int col, u16 v) {
  *(u16*)(xb + row * 1024 + ((col * 2) ^ ((row & 15) << 4))) = v;
}

// One dense layer over BOTH 64-row panels: wave computes rows [0,128) x cols [c0,c0+64).
// B-frags direct from global, fully unrolled K-loop, depth-2 rotating prefetch.
// pre[] carries this layer's step-0 B fragments in (already loaded by caller/previous
// layer) and, if Wnext!=null, next layer's step-0 fragments out.
template<int NK>
__device__ __forceinline__ void dense_layer(const u16* __restrict__ Wp,
                                            const u16* __restrict__ Wnext,
                                            const float* __restrict__ bias, int act,
                                            char* xb, int l15, int q, int c0,
                                            uint4 (&pre)[4])
{
  f32x4 acc[2][4][4];
  #pragma unroll
  for (int p = 0; p < 2; ++p)
    #pragma unroll
    for (int a = 0; a < 4; ++a)
      #pragma unroll
      for (int b = 0; b < 4; ++b) { f32x4 z = {0.f, 0.f, 0.f, 0.f}; acc[p][a][b] = z; }

  const u16* Wl = Wp + (c0 + l15) * 32 + q * 8;   // lane's base within a K32 block

  uint4 buf[3][4];
  #pragma unroll
  for (int ct = 0; ct < 4; ++ct) buf[0][ct] = pre[ct];
  if constexpr (NK > 1) {
    #pragma unroll
    for (int ct = 0; ct < 4; ++ct)
      buf[1][ct] = *reinterpret_cast<const uint4*>(Wl + 16384 + ct * 512);
  }

  #pragma unroll
  for (int i = 0; i < NK; ++i) {
    if (i + 2 < NK) {                      // depth-2 prefetch (static rotation)
      #pragma unroll
      for (int ct = 0; ct < 4; ++ct)
        buf[(i + 2) % 3][ct] =
            *reinterpret_cast<const uint4*>(Wl + (size_t)(i + 2) * 16384 + ct * 512);
    }
    __builtin_amdgcn_s_setprio(1);
    const int kb = i * 64 + q * 16;
    #pragma unroll
    for (int p = 0; p < 2; ++p)
      #pragma unroll
      for (int mt = 0; mt < 4; ++mt) {
        bf16x8 a = rdA(xb, p * 64 + mt * 16 + l15, kb);
        #pragma unroll
        for (int ct = 0; ct < 4; ++ct)
          acc[p][mt][ct] = __builtin_amdgcn_mfma_f32_16x16x32_bf16(
              a, __builtin_bit_cast(bf16x8, buf[i % 3][ct]), acc[p][mt][ct], 0, 0, 0);
      }
    __builtin_amdgcn_s_setprio(0);
  }

  if (Wnext != nullptr) {                  // warm-start next layer across the barrier
    const u16* Wn = Wnext + (c0 + l15) * 32 + q * 8;
    #pragma unroll
    for (int ct = 0; ct < 4; ++ct)
      pre[ct] = *reinterpret_cast<const uint4*>(Wn + ct * 512);
  }
  __syncthreads();   // all waves done READING xs

  float bv[4];
  #pragma unroll
  for (int ct = 0; ct < 4; ++ct) bv[ct] = bias[c0 + ct * 16 + l15];
  #pragma unroll
  for (int p = 0; p < 2; ++p)
    #pragma unroll
    for (int mt = 0; mt < 4; ++mt)
      #pragma unroll
      for (int ct = 0; ct < 4; ++ct)
        #pragma unroll
        for (int j = 0; j < 4; ++j) {
          int row = p * 64 + mt * 16 + q * 4 + j;
          float z = acc[p][mt][ct][j] + bv[ct];
          float h = act ? fmaxf(z, 0.f) : z / (1.f + __expf(-z));
          st16(xb, row, c0 + ct * 16 + l15, f2bf(h));
        }
  __syncthreads();   // xs updated for next layer
}

template<int CN>
__global__ __launch_bounds__(512, 2) void fused_kernel(
    const float* __restrict__ T, const u16* __restrict__ wsu,
    const float* __restrict__ wsf, float* __restrict__ Xout, float* __restrict__ Xcout,
    float* __restrict__ errPart, int n_arg)
{
  const int n = CN ? CN : n_arg;
  __shared__ u16 xs[MT * 512];       // 128 KiB, XOR-swizzled
  __shared__ float xo[MT * 20];      // X_hat rows for distortion (10 KiB)
  __shared__ float ts[MT * 16];      // T rows cached for distortion (8 KiB)
  __shared__ float scaleS[MT];
  __shared__ float ered[8][2];

  const int tid = threadIdx.x;
  const int blk = blockIdx.x;
  const int lane = tid & 63;
  const int wid = tid >> 6;          // 0..7
  const int l15 = lane & 15;
  const int q = lane >> 4;           // 0..3
  const int c0 = wid * 64;           // wave's output-column base (hidden layers)
  char* xb = (char*)xs;

  // ---- issue layer-0 (WI) B-frag loads first: latency hides under prologue ----
  uint4 pre[4];
  {
    const u16* WiL = wsu + WI_OFF + (c0 + l15) * 32 + q * 8;
    #pragma unroll
    for (int ct = 0; ct < 4; ++ct)
      pre[ct] = *reinterpret_cast<const uint4*>(WiL + ct * 512);
  }

  // ---- prologue: T load + normalize; 4 threads/row; cache T in LDS ----
  {
    const int r = tid >> 2, j = tid & 3;
    const size_t gr = (size_t)blk * MT + r;
    const float* tp = T + gr * n;
    float v[4]; float ss = 0.f;
    #pragma unroll
    for (int c = 0; c < 4; ++c) {
      int k = j * 4 + c;
      v[c] = (k < n) ? tp[k] : 0.f;
      ss += v[c] * v[c];
    }
    ss += __shfl_xor(ss, 1); ss += __shfl_xor(ss, 2);
    float norm = sqrtf(ss < 1e-12f ? 1e-12f : ss);
    float rn = 1.f / norm;
    if (j == 0) scaleS[r] = sqrtf(norm);
    #pragma unroll
    for (int c = 0; c < 4; ++c) {
      st16(xb, r, j * 4 + c, f2bf(v[c] * rn));
      st16(xb, r, 16 + j * 4 + c, 0);
      ts[r * 16 + j * 4 + c] = v[c];
    }
  }
  __syncthreads();

  dense_layer<1 >(wsu + WI_OFF, wsu + WH_OFF, wsf + BI_F, 0, xb, l15, q, c0, pre);
  dense_layer<16>(wsu + WH_OFF, wsu + WH_OFF + 262144, wsf + BH_F, 1, xb, l15, q, c0, pre);
  dense_layer<16>(wsu + WH_OFF + 262144, nullptr, wsf + BH_F + 512, 1, xb, l15, q, c0, pre);

  // ---- output layer: 8 waves, wave w owns rows w*16..+16, 32 padded cols ----
  {
    f32x4 oacc[2];
    { f32x4 z = {0.f, 0.f, 0.f, 0.f}; oacc[0] = z; oacc[1] = z; }
    const int bofs2 = l15 * 32 + q * 8;
    uint4 ob[3][2];
    #pragma unroll
    for (int s = 0; s < 2; ++s)
      #pragma unroll
      for (int ct = 0; ct < 2; ++ct)
        ob[s][ct] = *reinterpret_cast<const uint4*>(wsu + WO_OFF + s * 1024 + bofs2 + ct * 512);
    #pragma unroll
    for (int K = 0; K < 16; ++K) {
      if (K + 2 < 16) {
        #pragma unroll
        for (int ct = 0; ct < 2; ++ct)
          ob[(K + 2) % 3][ct] =
              *reinterpret_cast<const uint4*>(wsu + WO_OFF + (K + 2) * 1024 + bofs2 + ct * 512);
      }
      __builtin_amdgcn_s_setprio(1);
      bf16x8 a = rdA(xb, wid * 16 + l15, K * 64 + q * 16);
      #pragma unroll
      for (int ct = 0; ct < 2; ++ct)
        oacc[ct] = __builtin_amdgcn_mfma_f32_16x16x32_bf16(
            a, __builtin_bit_cast(bf16x8, ob[K % 3][ct]), oacc[ct], 0, 0, 0);
      __builtin_amdgcn_s_setprio(0);
    }
    #pragma unroll
    for (int ct = 0; ct < 2; ++ct)
      #pragma unroll
      for (int j = 0; j < 4; ++j) {
        int o = ct * 16 + l15;
        int row = wid * 16 + q * 4 + j;
        if (o <= n) {
          float val = (oacc[ct][j] + wsf[BO_F + o]) * scaleS[row];
          size_t gr = (size_t)blk * MT + row;
          float cv = fminf(fmaxf(val, -2.f), 2.f);
          Xout[gr * (n + 1) + o] = val;
          Xcout[gr * (n + 1) + o] = cv;
          xo[row * 20 + o] = val;
        }
      }
  }
  __syncthreads();

  // ---- distortion + squared-error partials: 4 threads/row, T from LDS ----
  {
    const int r = tid >> 2, j = tid & 3;
    float x[17], cx[17];
    #pragma unroll
    for (int i = 0; i < 17; ++i) {
      float v = (i <= n) ? xo[r * 20 + i] : 0.f;
      x[i] = v; cx[i] = fminf(fmaxf(v, -2.f), 2.f);
    }
    float e = 0.f, ec = 0.f;
    #pragma unroll
    for (int kk = 0; kk < 4; ++kk) {
      int k = j + 1 + kk * 4;
      if (k <= n) {
        float d = 0.f, dc = 0.f;
        #pragma unroll
        for (int i = 0; i < 16; ++i) {
          if (i + k <= 16) {
            if (i + k <= n) { d += x[i] * x[i + k]; dc += cx[i] * cx[i + k]; }
          }
        }
        float tvv = ts[r * 16 + (n - k)];
        float r1 = d - tvv, r2 = dc - tvv;
        e += r1 * r1; ec += r2 * r2;
      }
    }
    e += __shfl_xor(e, 1);  ec += __shfl_xor(ec, 1);
    e += __shfl_xor(e, 2);  ec += __shfl_xor(ec, 2);
    e += __shfl_xor(e, 4);  ec += __shfl_xor(ec, 4);
    e += __shfl_xor(e, 8);  ec += __shfl_xor(ec, 8);
    e += __shfl_xor(e, 16); ec += __shfl_xor(ec, 16);
    e += __shfl_xor(e, 32); ec += __shfl_xor(ec, 32);
    if (lane == 0) { ered[wid][0] = e; ered[wid][1] = ec; }
  }
  __syncthreads();
  if (tid == 0) {
    float e = 0.f, ec = 0.f;
    #pragma unroll
    for (int w = 0; w < 8; ++w) { e += ered[w][0]; ec += ered[w][1]; }
    errPart[blk * 2]     = e;      // per-block partial (no global atomics)
    errPart[blk * 2 + 1] = ec;
  }
}

__global__ void finalize_kernel(const float* __restrict__ part, float* __restrict__ e0,
                                float* __restrict__ e1, float inv)
{
  __shared__ float se[4][2];
  const int t = threadIdx.x;           // 256 threads
  float e = 0.f, ec = 0.f;
  for (int b = t; b < NBLK; b += 256) { e += part[2 * b]; ec += part[2 * b + 1]; }
  e += __shfl_xor(e, 1);  ec += __shfl_xor(ec, 1);
  e += __shfl_xor(e, 2);  ec += __shfl_xor(ec, 2);
  e += __shfl_xor(e, 4);  ec += __shfl_xor(ec, 4);
  e += __shfl_xor(e, 8);  ec += __shfl_xor(ec, 8);
  e += __shfl_xor(e, 16); ec += __shfl_xor(ec, 16);
  e += __shfl_xor(e, 32); ec += __shfl_xor(ec, 32);
  if ((t & 63) == 0) { se[t >> 6][0] = e; se[t >> 6][1] = ec; }
  __syncthreads();
  if (t == 0) {
    float te = 0.f, tec = 0.f;
    #pragma unroll
    for (int w = 0; w < 4; ++w) { te += se[w][0]; tec += se[w][1]; }
    e0[0] = te * inv;
    e1[0] = tec * inv;
  }
}

extern "C" void kernel_launch(void* const* d_in, const int* in_sizes, int n_in,
                              void* d_out, int out_size, void* d_ws, size_t ws_size,
                              hipStream_t stream)
{
  const float* T       = (const float*)d_in[0];
  const int*   variant = (const int*)d_in[2];
  const float* w_in    = (const float*)d_in[3];
  const float* b_in    = (const float*)d_in[4];
  const float* w_hid   = (const float*)d_in[5];
  const float* b_hid   = (const float*)d_in[6];
  const float* w_out   = (const float*)d_in[7];
  const float* b_out   = (const float*)d_in[8];
  const int n = in_sizes[0] / BATCH;

  u16* wsu = (u16*)d_ws;
  float* wsf = (float*)((char*)d_ws + (size_t)WS_USH * 2);
  float* out = (float*)d_out;
  const size_t xe = (size_t)BATCH * (n + 1);
  float* Xo  = out;
  float* eP  = out + xe;
  float* Xc  = out + xe + 1;
  float* ecP = out + 2 * xe + 1;

  const int prepBlocks = (PREP_TOTAL + 255) / 256;
  prep_kernel<<<prepBlocks, 256, 0, stream>>>(w_in, b_in, w_hid, b_hid, w_out, b_out,
                                              variant, n, wsu, wsf);
  if (n == 16)
    fused_kernel<16><<<NBLK, 512, 0, stream>>>(T, wsu, wsf, Xo, Xc, wsf + PART_F, n);
  else
    fused_kernel<0><<<NBLK, 512, 0, stream>>>(T, wsu, wsf, Xo, Xc, wsf + PART_F, n);
  finalize_kernel<<<1, 256, 0, stream>>>(wsf + PART_F, eP, ecP, 1.f / (float)((size_t)BATCH * n));
}

// Round 8
// 165.831 us; speedup vs baseline: 1.4250x; 1.4250x over previous
//
#include <hip/hip_runtime.h>

#define BATCH 65536
#define MT 128                // rows per block
#define NBLK (BATCH / MT)     // 512

typedef unsigned short u16;
typedef __bf16 bf16x8 __attribute__((ext_vector_type(8)));
typedef float f32x4 __attribute__((ext_vector_type(4)));

// d_ws layout (u16 element offsets) — fragment-native weight layouts:
//   W'[K32][col][g][e]: element (col, k) at [K32][col][k>>3 & 3][k&7], k = K32*32+g*8+e
#define WI_OFF 0              // [1][512][4][8]   (k>=16 zero)
#define WH_OFF 16384          // [2][16][512][4][8]
#define WO_OFF 540672         // [16][32][4][8]   (cols o padded 17->32)
#define WS_USH 557056
// float region at (char*)ws + WS_USH*2
#define BI_F 0
#define BH_F 512
#define BO_F 1536
#define PART_F 1568           // [NBLK][2] per-block error partials
#define PREP_WH 65536
#define PREP_WI 2048
#define PREP_WO 2048
#define PREP_SC 1568
#define PREP_TOTAL (PREP_WH + PREP_WI + PREP_WO + PREP_SC)

__device__ inline u16 f2bf(float f) {
  union { float f; unsigned u; } v; v.f = f;
  unsigned u = v.u + 0x7fffu + ((v.u >> 16) & 1u);   // RNE
  return (u16)(u >> 16);
}

__global__ void prep_kernel(const float* __restrict__ w_in, const float* __restrict__ b_in,
                            const float* __restrict__ w_hid, const float* __restrict__ b_hid,
                            const float* __restrict__ w_out, const float* __restrict__ b_out,
                            const int* __restrict__ variant, int n,
                            u16* __restrict__ wsu, float* __restrict__ wsf)
{
  const int model = (n - 5) * 16 + variant[0];
  const int i = blockIdx.x * 256 + threadIdx.x;
  if (i < PREP_WH) {
    int g = i & 3, col = (i >> 2) & 511, K32 = (i >> 11) & 15, l = i >> 15;
    const float* src = w_hid + (size_t)model * 524288 + (size_t)l * 262144 + col * 512 + K32 * 32 + g * 8;
    u16* dst = wsu + WH_OFF + (size_t)i * 8;
    #pragma unroll
    for (int e = 0; e < 8; ++e) dst[e] = f2bf(src[e]);
  } else if (i < PREP_WH + PREP_WI) {
    int j = i - PREP_WH;
    int g = j & 3, col = j >> 2;
    u16* dst = wsu + WI_OFF + (size_t)j * 8;
    #pragma unroll
    for (int e = 0; e < 8; ++e) {
      int k = g * 8 + e;
      dst[e] = (k < 16) ? f2bf(w_in[(size_t)model * 8192 + col * 16 + k]) : (u16)0;
    }
  } else if (i < PREP_WH + PREP_WI + PREP_WO) {
    int j = i - PREP_WH - PREP_WI;
    int g = j & 3, col = (j >> 2) & 31, K32 = j >> 7;
    u16* dst = wsu + WO_OFF + (size_t)j * 8;
    #pragma unroll
    for (int e = 0; e < 8; ++e) {
      int k = K32 * 32 + g * 8 + e;
      dst[e] = (col < 17) ? f2bf(w_out[(size_t)model * 8704 + col * 512 + k]) : (u16)0;
    }
  } else if (i < PREP_TOTAL) {
    int j = i - PREP_WH - PREP_WI - PREP_WO;
    if (j < 512)       wsf[BI_F + j] = b_in[(size_t)model * 512 + j];
    else if (j < 1536) wsf[BH_F + (j - 512)] = b_hid[(size_t)model * 1024 + (j - 512)];
    else               { int o = j - 1536; wsf[BO_F + o] = (o < 17) ? b_out[(size_t)model * 17 + o] : 0.f; }
  }
}

// xs layout: byte = row*1024 + ((col*2) ^ ((row&15)<<4))
__device__ __forceinline__ bf16x8 rdA(const char* xb, int row, int kbyte) {
  return *reinterpret_cast<const bf16x8*>(xb + row * 1024 + (kbyte ^ ((row & 15) << 4)));
}
__device__ __forceinline__ void st16(char* xb, int row, int col, u16 v) {
  *(u16*)(xb + row * 1024 + ((col * 2) ^ ((row & 15) << 4))) = v;
}

// One dense layer, 16-wave geometry: wave owns rows [0,128) x cols [c0,c0+32).
// acc[8][2] = 64 accumulator regs/wave -> fits 4 waves/SIMD budget.
// B-frags direct from global (L2-resident), depth-1 ping-pong prefetch.
template<int NK>
__device__ __forceinline__ void dense_layer(const u16* __restrict__ Wp,
                                            const float* __restrict__ bias, int act,
                                            char* xb, int l15, int q, int c0)
{
  f32x4 acc[8][2];
  #pragma unroll
  for (int a = 0; a < 8; ++a)
    #pragma unroll
    for (int b = 0; b < 2; ++b) { f32x4 z = {0.f, 0.f, 0.f, 0.f}; acc[a][b] = z; }

  const u16* Wl = Wp + (c0 + l15) * 32 + q * 8;   // lane's base within a K32 block

  if constexpr (NK == 1) {
    uint4 b0[2];
    #pragma unroll
    for (int ct = 0; ct < 2; ++ct)
      b0[ct] = *reinterpret_cast<const uint4*>(Wl + ct * 512);
    const int kb = q * 16;
    #pragma unroll
    for (int mt = 0; mt < 8; ++mt) {
      bf16x8 a = rdA(xb, mt * 16 + l15, kb);
      #pragma unroll
      for (int ct = 0; ct < 2; ++ct)
        acc[mt][ct] = __builtin_amdgcn_mfma_f32_16x16x32_bf16(
            a, __builtin_bit_cast(bf16x8, b0[ct]), acc[mt][ct], 0, 0, 0);
    }
  } else {
    uint4 bc[2], bn[2];
    #pragma unroll
    for (int ct = 0; ct < 2; ++ct)
      bc[ct] = *reinterpret_cast<const uint4*>(Wl + ct * 512);
    #pragma unroll 1
    for (int i = 0; i < NK; i += 2) {
      // prefetch step i+1
      {
        const u16* p = Wl + (size_t)(i + 1) * 16384;
        #pragma unroll
        for (int ct = 0; ct < 2; ++ct)
          bn[ct] = *reinterpret_cast<const uint4*>(p + ct * 512);
      }
      // compute step i with bc
      {
        const int kb = i * 64 + q * 16;
        #pragma unroll
        for (int mt = 0; mt < 8; ++mt) {
          bf16x8 a = rdA(xb, mt * 16 + l15, kb);
          #pragma unroll
          for (int ct = 0; ct < 2; ++ct)
            acc[mt][ct] = __builtin_amdgcn_mfma_f32_16x16x32_bf16(
                a, __builtin_bit_cast(bf16x8, bc[ct]), acc[mt][ct], 0, 0, 0);
        }
      }
      // prefetch step i+2 (wraps harmlessly on last iteration)
      {
        const u16* p = Wl + (size_t)((i + 2) & (NK - 1)) * 16384;
        #pragma unroll
        for (int ct = 0; ct < 2; ++ct)
          bc[ct] = *reinterpret_cast<const uint4*>(p + ct * 512);
      }
      // compute step i+1 with bn
      {
        const int kb = (i + 1) * 64 + q * 16;
        #pragma unroll
        for (int mt = 0; mt < 8; ++mt) {
          bf16x8 a = rdA(xb, mt * 16 + l15, kb);
          #pragma unroll
          for (int ct = 0; ct < 2; ++ct)
            acc[mt][ct] = __builtin_amdgcn_mfma_f32_16x16x32_bf16(
                a, __builtin_bit_cast(bf16x8, bn[ct]), acc[mt][ct], 0, 0, 0);
        }
      }
    }
  }
  __syncthreads();   // all waves done READING xs

  float bv[2];
  #pragma unroll
  for (int ct = 0; ct < 2; ++ct) bv[ct] = bias[c0 + ct * 16 + l15];
  #pragma unroll
  for (int mt = 0; mt < 8; ++mt)
    #pragma unroll
    for (int ct = 0; ct < 2; ++ct)
      #pragma unroll
      for (int j = 0; j < 4; ++j) {
        int row = mt * 16 + q * 4 + j;
        float z = acc[mt][ct][j] + bv[ct];
        float h = act ? fmaxf(z, 0.f) : z / (1.f + __expf(-z));
        st16(xb, row, c0 + ct * 16 + l15, f2bf(h));
      }
  __syncthreads();   // xs updated for next layer
}

template<int CN>
__global__ __launch_bounds__(1024, 4) void fused_kernel(
    const float* __restrict__ T, const u16* __restrict__ wsu,
    const float* __restrict__ wsf, float* __restrict__ Xout, float* __restrict__ Xcout,
    float* __restrict__ errPart, int n_arg)
{
  const int n = CN ? CN : n_arg;
  __shared__ u16 xs[MT * 512];       // 128 KiB, XOR-swizzled
  __shared__ float xo[MT * 20];      // X_hat rows for distortion (10 KiB)
  __shared__ float ts[MT * 16];      // T rows cached for distortion (8 KiB)
  __shared__ float scaleS[MT];
  __shared__ float ered[16][2];

  const int tid = threadIdx.x;
  const int blk = blockIdx.x;
  const int lane = tid & 63;
  const int wid = tid >> 6;          // 0..15
  const int l15 = lane & 15;
  const int q = lane >> 4;           // 0..3
  const int c0 = wid * 32;           // wave's output-column base (hidden layers)
  char* xb = (char*)xs;

  // ---- prologue: T load + normalize; 8 threads/row; cache T in LDS ----
  {
    const int r = tid >> 3, j = tid & 7;
    const size_t gr = (size_t)blk * MT + r;
    const float* tp = T + gr * n;
    const int k0 = 2 * j, k1 = 2 * j + 1;
    float v0 = (k0 < n) ? tp[k0] : 0.f;
    float v1 = (k1 < n) ? tp[k1] : 0.f;
    float ss = v0 * v0 + v1 * v1;
    ss += __shfl_xor(ss, 1); ss += __shfl_xor(ss, 2); ss += __shfl_xor(ss, 4);
    float norm = sqrtf(ss < 1e-12f ? 1e-12f : ss);
    float rn = 1.f / norm;
    if (j == 0) scaleS[r] = sqrtf(norm);
    st16(xb, r, k0, f2bf(v0 * rn));
    st16(xb, r, k1, f2bf(v1 * rn));
    st16(xb, r, 16 + k0, 0);
    st16(xb, r, 16 + k1, 0);
    ts[r * 16 + k0] = v0;
    ts[r * 16 + k1] = v1;
  }
  __syncthreads();

  dense_layer<1 >(wsu + WI_OFF,          wsf + BI_F,       0, xb, l15, q, c0);
  dense_layer<16>(wsu + WH_OFF,          wsf + BH_F,       1, xb, l15, q, c0);
  dense_layer<16>(wsu + WH_OFF + 262144, wsf + BH_F + 512, 1, xb, l15, q, c0);

  // ---- output layer: 16 waves; wave w -> rows (w>>1)*16..+16, col-half (w&1) ----
  {
    const int rg = wid >> 1;         // 0..7
    const int ct = wid & 1;          // 0..1
    f32x4 oacc = {0.f, 0.f, 0.f, 0.f};
    const u16* WoL = wsu + WO_OFF + (ct * 16 + l15) * 32 + q * 8;
    uint4 ob = *reinterpret_cast<const uint4*>(WoL);
    #pragma unroll 1
    for (int K = 0; K < 16; K += 2) {
      uint4 on = *reinterpret_cast<const uint4*>(WoL + (size_t)(K + 1) * 1024);
      {
        bf16x8 a = rdA(xb, rg * 16 + l15, K * 64 + q * 16);
        oacc = __builtin_amdgcn_mfma_f32_16x16x32_bf16(
            a, __builtin_bit_cast(bf16x8, ob), oacc, 0, 0, 0);
      }
      ob = *reinterpret_cast<const uint4*>(WoL + (size_t)((K + 2) & 15) * 1024);
      {
        bf16x8 a = rdA(xb, rg * 16 + l15, (K + 1) * 64 + q * 16);
        oacc = __builtin_amdgcn_mfma_f32_16x16x32_bf16(
            a, __builtin_bit_cast(bf16x8, on), oacc, 0, 0, 0);
      }
    }
    const int o = ct * 16 + l15;
    #pragma unroll
    for (int j = 0; j < 4; ++j) {
      int row = rg * 16 + q * 4 + j;
      if (o <= n) {
        float val = (oacc[j] + wsf[BO_F + o]) * scaleS[row];
        size_t gr = (size_t)blk * MT + row;
        float cv = fminf(fmaxf(val, -2.f), 2.f);
        Xout[gr * (n + 1) + o] = val;
        Xcout[gr * (n + 1) + o] = cv;
        xo[row * 20 + o] = val;
      }
    }
  }
  __syncthreads();

  // ---- distortion + squared-error partials: 8 threads/row, T from LDS ----
  {
    const int r = tid >> 3, j = tid & 7;
    float x[17], cx[17];
    #pragma unroll
    for (int i = 0; i < 17; ++i) {
      float v = (i <= n) ? xo[r * 20 + i] : 0.f;
      x[i] = v; cx[i] = fminf(fmaxf(v, -2.f), 2.f);
    }
    float e = 0.f, ec = 0.f;
    #pragma unroll
    for (int kk = 0; kk < 2; ++kk) {
      int k = j + 1 + kk * 8;
      if (k <= n) {
        float d = 0.f, dc = 0.f;
        #pragma unroll
        for (int i = 0; i < 16; ++i) {
          if (i + k <= 16) {
            if (i + k <= n) { d += x[i] * x[i + k]; dc += cx[i] * cx[i + k]; }
          }
        }
        float tvv = ts[r * 16 + (n - k)];
        float r1 = d - tvv, r2 = dc - tvv;
        e += r1 * r1; ec += r2 * r2;
      }
    }
    e += __shfl_xor(e, 1);  ec += __shfl_xor(ec, 1);
    e += __shfl_xor(e, 2);  ec += __shfl_xor(ec, 2);
    e += __shfl_xor(e, 4);  ec += __shfl_xor(ec, 4);
    e += __shfl_xor(e, 8);  ec += __shfl_xor(ec, 8);
    e += __shfl_xor(e, 16); ec += __shfl_xor(ec, 16);
    e += __shfl_xor(e, 32); ec += __shfl_xor(ec, 32);
    if (lane == 0) { ered[wid][0] = e; ered[wid][1] = ec; }
  }
  __syncthreads();
  if (tid == 0) {
    float e = 0.f, ec = 0.f;
    #pragma unroll
    for (int w = 0; w < 16; ++w) { e += ered[w][0]; ec += ered[w][1]; }
    errPart[blk * 2]     = e;      // per-block partial (no global atomics)
    errPart[blk * 2 + 1] = ec;
  }
}

__global__ void finalize_kernel(const float* __restrict__ part, float* __restrict__ e0,
                                float* __restrict__ e1, float inv)
{
  __shared__ float se[4][2];
  const int t = threadIdx.x;           // 256 threads
  float e = 0.f, ec = 0.f;
  for (int b = t; b < NBLK; b += 256) { e += part[2 * b]; ec += part[2 * b + 1]; }
  e += __shfl_xor(e, 1);  ec += __shfl_xor(ec, 1);
  e += __shfl_xor(e, 2);  ec += __shfl_xor(ec, 2);
  e += __shfl_xor(e, 4);  ec += __shfl_xor(ec, 4);
  e += __shfl_xor(e, 8);  ec += __shfl_xor(ec, 8);
  e += __shfl_xor(e, 16); ec += __shfl_xor(ec, 16);
  e += __shfl_xor(e, 32); ec += __shfl_xor(ec, 32);
  if ((t & 63) == 0) { se[t >> 6][0] = e; se[t >> 6][1] = ec; }
  __syncthreads();
  if (t == 0) {
    float te = 0.f, tec = 0.f;
    #pragma unroll
    for (int w = 0; w < 4; ++w) { te += se[w][0]; tec += se[w][1]; }
    e0[0] = te * inv;
    e1[0] = tec * inv;
  }
}

extern "C" void kernel_launch(void* const* d_in, const int* in_sizes, int n_in,
                              void* d_out, int out_size, void* d_ws, size_t ws_size,
                              hipStream_t stream)
{
  const float* T       = (const float*)d_in[0];
  const int*   variant = (const int*)d_in[2];
  const float* w_in    = (const float*)d_in[3];
  const float* b_in    = (const float*)d_in[4];
  const float* w_hid   = (const float*)d_in[5];
  const float* b_hid   = (const float*)d_in[6];
  const float* w_out   = (const float*)d_in[7];
  const float* b_out   = (const float*)d_in[8];
  const int n = in_sizes[0] / BATCH;

  u16* wsu = (u16*)d_ws;
  float* wsf = (float*)((char*)d_ws + (size_t)WS_USH * 2);
  float* out = (float*)d_out;
  const size_t xe = (size_t)BATCH * (n + 1);
  float* Xo  = out;
  float* eP  = out + xe;
  float* Xc  = out + xe + 1;
  float* ecP = out + 2 * xe + 1;

  const int prepBlocks = (PREP_TOTAL + 255) / 256;
  prep_kernel<<<prepBlocks, 256, 0, stream>>>(w_in, b_in, w_hid, b_hid, w_out, b_out,
                                              variant, n, wsu, wsf);
  if (n == 16)
    fused_kernel<16><<<NBLK, 1024, 0, stream>>>(T, wsu, wsf, Xo, Xc, wsf + PART_F, n);
  else
    fused_kernel<0><<<NBLK, 1024, 0, stream>>>(T, wsu, wsf, Xo, Xc, wsf + PART_F, n);
  finalize_kernel<<<1, 256, 0, stream>>>(wsf + PART_F, eP, ecP, 1.f / (float)((size_t)BATCH * n));
}

// Round 9
// 152.316 us; speedup vs baseline: 1.5514x; 1.0887x over previous
//
#include <hip/hip_runtime.h>

#define BATCH 65536
#define MT 128                // rows per block (2 panels of 64)
#define NBLK (BATCH / MT)     // 512

typedef unsigned short u16;
typedef __bf16 bf16x8 __attribute__((ext_vector_type(8)));
typedef float f32x4 __attribute__((ext_vector_type(4)));

// d_ws layout (u16 element offsets) — fragment-native weight layouts:
//   W'[K32][col][g][e]: element (col, k) at [K32][col][k>>3 & 3][k&7], k = K32*32+g*8+e
#define WI_OFF 0              // [1][512][4][8]   (k>=16 zero)
#define WH_OFF 16384          // [2][16][512][4][8]
#define WO_OFF 540672         // [16][32][4][8]   (cols o padded 17->32)
#define WS_USH 557056
// float region at (char*)ws + WS_USH*2
#define BI_F 0
#define BH_F 512
#define BO_F 1536
#define PART_F 1568           // [NBLK][2] per-block error partials
#define PREP_WH 65536
#define PREP_WI 2048
#define PREP_WO 2048
#define PREP_SC 1568
#define PREP_TOTAL (PREP_WH + PREP_WI + PREP_WO + PREP_SC)

__device__ inline u16 f2bf(float f) {
  union { float f; unsigned u; } v; v.f = f;
  unsigned u = v.u + 0x7fffu + ((v.u >> 16) & 1u);   // RNE
  return (u16)(u >> 16);
}

__global__ void prep_kernel(const float* __restrict__ w_in, const float* __restrict__ b_in,
                            const float* __restrict__ w_hid, const float* __restrict__ b_hid,
                            const float* __restrict__ w_out, const float* __restrict__ b_out,
                            const int* __restrict__ variant, int n,
                            u16* __restrict__ wsu, float* __restrict__ wsf)
{
  const int model = (n - 5) * 16 + variant[0];
  const int i = blockIdx.x * 256 + threadIdx.x;
  if (i < PREP_WH) {
    int g = i & 3, col = (i >> 2) & 511, K32 = (i >> 11) & 15, l = i >> 15;
    const float* src = w_hid + (size_t)model * 524288 + (size_t)l * 262144 + col * 512 + K32 * 32 + g * 8;
    u16* dst = wsu + WH_OFF + (size_t)i * 8;
    #pragma unroll
    for (int e = 0; e < 8; ++e) dst[e] = f2bf(src[e]);
  } else if (i < PREP_WH + PREP_WI) {
    int j = i - PREP_WH;
    int g = j & 3, col = j >> 2;
    u16* dst = wsu + WI_OFF + (size_t)j * 8;
    #pragma unroll
    for (int e = 0; e < 8; ++e) {
      int k = g * 8 + e;
      dst[e] = (k < 16) ? f2bf(w_in[(size_t)model * 8192 + col * 16 + k]) : (u16)0;
    }
  } else if (i < PREP_WH + PREP_WI + PREP_WO) {
    int j = i - PREP_WH - PREP_WI;
    int g = j & 3, col = (j >> 2) & 31, K32 = j >> 7;
    u16* dst = wsu + WO_OFF + (size_t)j * 8;
    #pragma unroll
    for (int e = 0; e < 8; ++e) {
      int k = K32 * 32 + g * 8 + e;
      dst[e] = (col < 17) ? f2bf(w_out[(size_t)model * 8704 + col * 512 + k]) : (u16)0;
    }
  } else if (i < PREP_TOTAL) {
    int j = i - PREP_WH - PREP_WI - PREP_WO;
    if (j < 512)       wsf[BI_F + j] = b_in[(size_t)model * 512 + j];
    else if (j < 1536) wsf[BH_F + (j - 512)] = b_hid[(size_t)model * 1024 + (j - 512)];
    else               { int o = j - 1536; wsf[BO_F + o] = (o < 17) ? b_out[(size_t)model * 17 + o] : 0.f; }
  }
}

// xs layout: byte = row*1024 + ((col*2) ^ ((row&15)<<4))
__device__ __forceinline__ bf16x8 rdA(const char* xb, int row, int kbyte) {
  return *reinterpret_cast<const bf16x8*>(xb + row * 1024 + (kbyte ^ ((row & 15) << 4)));
}
__device__ __forceinline__ void st16(char* xb, int row, int col, u16 v) {
  *(u16*)(xb + row * 1024 + ((col * 2) ^ ((row & 15) << 4))) = v;
}

// One dense layer, 2Mx4N wave grid: wave owns rows [r0,r0+64) x cols [c0,c0+128).
// acc[4][8] = 128 acc regs; B-frags (8/step) direct from global, ping-pong prefetch.
// A-redundancy 4x (vs 8x in the 1x8 grid) -> LDS read pipe balanced with MFMA.
template<int NK>
__device__ __forceinline__ void dense_layer(const u16* __restrict__ Wp,
                                            const float* __restrict__ bias, int act,
                                            char* xb, int l15, int q, int r0, int c0)
{
  f32x4 acc[4][8];
  #pragma unroll
  for (int a = 0; a < 4; ++a)
    #pragma unroll
    for (int b = 0; b < 8; ++b) { f32x4 z = {0.f, 0.f, 0.f, 0.f}; acc[a][b] = z; }

  const u16* Wl = Wp + (c0 + l15) * 32 + q * 8;   // lane's base within a K32 block

  if constexpr (NK == 1) {
    uint4 b0[8];
    #pragma unroll
    for (int ct = 0; ct < 8; ++ct)
      b0[ct] = *reinterpret_cast<const uint4*>(Wl + ct * 512);
    const int kb = q * 16;
    #pragma unroll
    for (int mt = 0; mt < 4; ++mt) {
      bf16x8 a = rdA(xb, r0 + mt * 16 + l15, kb);
      #pragma unroll
      for (int ct = 0; ct < 8; ++ct)
        acc[mt][ct] = __builtin_amdgcn_mfma_f32_16x16x32_bf16(
            a, __builtin_bit_cast(bf16x8, b0[ct]), acc[mt][ct], 0, 0, 0);
    }
  } else {
    uint4 bc[8], bn[8];
    #pragma unroll
    for (int ct = 0; ct < 8; ++ct)
      bc[ct] = *reinterpret_cast<const uint4*>(Wl + ct * 512);
    #pragma unroll 1
    for (int i = 0; i < NK; i += 2) {
      // prefetch step i+1
      {
        const u16* p = Wl + (size_t)(i + 1) * 16384;
        #pragma unroll
        for (int ct = 0; ct < 8; ++ct)
          bn[ct] = *reinterpret_cast<const uint4*>(p + ct * 512);
      }
      // compute step i with bc
      {
        const int kb = i * 64 + q * 16;
        #pragma unroll
        for (int mt = 0; mt < 4; ++mt) {
          bf16x8 a = rdA(xb, r0 + mt * 16 + l15, kb);
          #pragma unroll
          for (int ct = 0; ct < 8; ++ct)
            acc[mt][ct] = __builtin_amdgcn_mfma_f32_16x16x32_bf16(
                a, __builtin_bit_cast(bf16x8, bc[ct]), acc[mt][ct], 0, 0, 0);
        }
      }
      // prefetch step i+2 (wraps harmlessly on last iteration)
      {
        const u16* p = Wl + (size_t)((i + 2) & (NK - 1)) * 16384;
        #pragma unroll
        for (int ct = 0; ct < 8; ++ct)
          bc[ct] = *reinterpret_cast<const uint4*>(p + ct * 512);
      }
      // compute step i+1 with bn
      {
        const int kb = (i + 1) * 64 + q * 16;
        #pragma unroll
        for (int mt = 0; mt < 4; ++mt) {
          bf16x8 a = rdA(xb, r0 + mt * 16 + l15, kb);
          #pragma unroll
          for (int ct = 0; ct < 8; ++ct)
            acc[mt][ct] = __builtin_amdgcn_mfma_f32_16x16x32_bf16(
                a, __builtin_bit_cast(bf16x8, bn[ct]), acc[mt][ct], 0, 0, 0);
        }
      }
    }
  }
  __syncthreads();   // all waves done READING xs

  float bv[8];
  #pragma unroll
  for (int ct = 0; ct < 8; ++ct) bv[ct] = bias[c0 + ct * 16 + l15];
  #pragma unroll
  for (int mt = 0; mt < 4; ++mt)
    #pragma unroll
    for (int ct = 0; ct < 8; ++ct)
      #pragma unroll
      for (int j = 0; j < 4; ++j) {
        int row = r0 + mt * 16 + q * 4 + j;
        float z = acc[mt][ct][j] + bv[ct];
        float h = act ? fmaxf(z, 0.f) : z / (1.f + __expf(-z));
        st16(xb, row, c0 + ct * 16 + l15, f2bf(h));
      }
  __syncthreads();   // xs updated for next layer
}

template<int CN>
__global__ __launch_bounds__(512, 2) void fused_kernel(
    const float* __restrict__ T, const u16* __restrict__ wsu,
    const float* __restrict__ wsf, float* __restrict__ Xout, float* __restrict__ Xcout,
    float* __restrict__ errPart, int n_arg)
{
  const int n = CN ? CN : n_arg;
  __shared__ u16 xs[MT * 512];       // 128 KiB, XOR-swizzled
  __shared__ float xo[MT * 20];      // X_hat rows for distortion (10 KiB)
  __shared__ float ts[MT * 16];      // T rows cached for distortion (8 KiB)
  __shared__ float scaleS[MT];
  __shared__ float ered[8][2];

  const int tid = threadIdx.x;
  const int blk = blockIdx.x;
  const int lane = tid & 63;
  const int wid = tid >> 6;          // 0..7
  const int l15 = lane & 15;
  const int q = lane >> 4;           // 0..3
  const int r0 = (wid >> 2) * 64;    // wave's row base: 0 or 64
  const int c0 = (wid & 3) * 128;    // wave's col base: 0..384
  char* xb = (char*)xs;

  // ---- prologue: T load + normalize; 4 threads/row; cache T in LDS ----
  {
    const int r = tid >> 2, j = tid & 3;
    const size_t gr = (size_t)blk * MT + r;
    const float* tp = T + gr * n;
    float v[4]; float ss = 0.f;
    #pragma unroll
    for (int c = 0; c < 4; ++c) {
      int k = j * 4 + c;
      v[c] = (k < n) ? tp[k] : 0.f;
      ss += v[c] * v[c];
    }
    ss += __shfl_xor(ss, 1); ss += __shfl_xor(ss, 2);
    float norm = sqrtf(ss < 1e-12f ? 1e-12f : ss);
    float rn = 1.f / norm;
    if (j == 0) scaleS[r] = sqrtf(norm);
    #pragma unroll
    for (int c = 0; c < 4; ++c) {
      st16(xb, r, j * 4 + c, f2bf(v[c] * rn));
      st16(xb, r, 16 + j * 4 + c, 0);
      ts[r * 16 + j * 4 + c] = v[c];
    }
  }
  __syncthreads();

  dense_layer<1 >(wsu + WI_OFF,          wsf + BI_F,       0, xb, l15, q, r0, c0);
  dense_layer<16>(wsu + WH_OFF,          wsf + BH_F,       1, xb, l15, q, r0, c0);
  dense_layer<16>(wsu + WH_OFF + 262144, wsf + BH_F + 512, 1, xb, l15, q, r0, c0);

  // ---- output layer: 8 waves, wave w owns rows w*16..+16, 32 padded cols ----
  {
    f32x4 oacc[2];
    { f32x4 z = {0.f, 0.f, 0.f, 0.f}; oacc[0] = z; oacc[1] = z; }
    const int bofs2 = l15 * 32 + q * 8;
    uint4 ob[2], on[2];
    #pragma unroll
    for (int ct = 0; ct < 2; ++ct)
      ob[ct] = *reinterpret_cast<const uint4*>(wsu + WO_OFF + bofs2 + ct * 512);
    #pragma unroll 1
    for (int K2 = 0; K2 < 16; K2 += 2) {
      #pragma unroll
      for (int ct = 0; ct < 2; ++ct)
        on[ct] = *reinterpret_cast<const uint4*>(wsu + WO_OFF + (size_t)(K2 + 1) * 1024 + bofs2 + ct * 512);
      {
        bf16x8 a = rdA(xb, wid * 16 + l15, K2 * 64 + q * 16);
        #pragma unroll
        for (int ct = 0; ct < 2; ++ct)
          oacc[ct] = __builtin_amdgcn_mfma_f32_16x16x32_bf16(
              a, __builtin_bit_cast(bf16x8, ob[ct]), oacc[ct], 0, 0, 0);
      }
      #pragma unroll
      for (int ct = 0; ct < 2; ++ct)
        ob[ct] = *reinterpret_cast<const uint4*>(wsu + WO_OFF + (size_t)((K2 + 2) & 15) * 1024 + bofs2 + ct * 512);
      {
        bf16x8 a = rdA(xb, wid * 16 + l15, (K2 + 1) * 64 + q * 16);
        #pragma unroll
        for (int ct = 0; ct < 2; ++ct)
          oacc[ct] = __builtin_amdgcn_mfma_f32_16x16x32_bf16(
              a, __builtin_bit_cast(bf16x8, on[ct]), oacc[ct], 0, 0, 0);
      }
    }
    #pragma unroll
    for (int ct = 0; ct < 2; ++ct)
      #pragma unroll
      for (int j = 0; j < 4; ++j) {
        int o = ct * 16 + l15;
        int row = wid * 16 + q * 4 + j;
        if (o <= n) {
          float val = (oacc[ct][j] + wsf[BO_F + o]) * scaleS[row];
          size_t gr = (size_t)blk * MT + row;
          float cv = fminf(fmaxf(val, -2.f), 2.f);
          Xout[gr * (n + 1) + o] = val;
          Xcout[gr * (n + 1) + o] = cv;
          xo[row * 20 + o] = val;
        }
      }
  }
  __syncthreads();

  // ---- distortion + squared-error partials: 4 threads/row, T from LDS ----
  {
    const int r = tid >> 2, j = tid & 3;
    float x[17], cx[17];
    #pragma unroll
    for (int i = 0; i < 17; ++i) {
      float v = (i <= n) ? xo[r * 20 + i] : 0.f;
      x[i] = v; cx[i] = fminf(fmaxf(v, -2.f), 2.f);
    }
    float e = 0.f, ec = 0.f;
    #pragma unroll
    for (int kk = 0; kk < 4; ++kk) {
      int k = j + 1 + kk * 4;
      if (k <= n) {
        float d = 0.f, dc = 0.f;
        #pragma unroll
        for (int i = 0; i < 16; ++i) {
          if (i + k <= 16) {
            if (i + k <= n) { d += x[i] * x[i + k]; dc += cx[i] * cx[i + k]; }
          }
        }
        float tvv = ts[r * 16 + (n - k)];
        float r1 = d - tvv, r2 = dc - tvv;
        e += r1 * r1; ec += r2 * r2;
      }
    }
    e += __shfl_xor(e, 1);  ec += __shfl_xor(ec, 1);
    e += __shfl_xor(e, 2);  ec += __shfl_xor(ec, 2);
    e += __shfl_xor(e, 4);  ec += __shfl_xor(ec, 4);
    e += __shfl_xor(e, 8);  ec += __shfl_xor(ec, 8);
    e += __shfl_xor(e, 16); ec += __shfl_xor(ec, 16);
    e += __shfl_xor(e, 32); ec += __shfl_xor(ec, 32);
    if (lane == 0) { ered[wid][0] = e; ered[wid][1] = ec; }
  }
  __syncthreads();
  if (tid == 0) {
    float e = 0.f, ec = 0.f;
    #pragma unroll
    for (int w = 0; w < 8; ++w) { e += ered[w][0]; ec += ered[w][1]; }
    errPart[blk * 2]     = e;      // per-block partial (no global atomics)
    errPart[blk * 2 + 1] = ec;
  }
}

__global__ void finalize_kernel(const float* __restrict__ part, float* __restrict__ e0,
                                float* __restrict__ e1, float inv)
{
  __shared__ float se[4][2];
  const int t = threadIdx.x;           // 256 threads
  float e = 0.f, ec = 0.f;
  for (int b = t; b < NBLK; b += 256) { e += part[2 * b]; ec += part[2 * b + 1]; }
  e += __shfl_xor(e, 1);  ec += __shfl_xor(ec, 1);
  e += __shfl_xor(e, 2);  ec += __shfl_xor(ec, 2);
  e += __shfl_xor(e, 4);  ec += __shfl_xor(ec, 4);
  e += __shfl_xor(e, 8);  ec += __shfl_xor(ec, 8);
  e += __shfl_xor(e, 16); ec += __shfl_xor(ec, 16);
  e += __shfl_xor(e, 32); ec += __shfl_xor(ec, 32);
  if ((t & 63) == 0) { se[t >> 6][0] = e; se[t >> 6][1] = ec; }
  __syncthreads();
  if (t == 0) {
    float te = 0.f, tec = 0.f;
    #pragma unroll
    for (int w = 0; w < 4; ++w) { te += se[w][0]; tec += se[w][1]; }
    e0[0] = te * inv;
    e1[0] = tec * inv;
  }
}

extern "C" void kernel_launch(void* const* d_in, const int* in_sizes, int n_in,
                              void* d_out, int out_size, void* d_ws, size_t ws_size,
                              hipStream_t stream)
{
  const float* T       = (const float*)d_in[0];
  const int*   variant = (const int*)d_in[2];
  const float* w_in    = (const float*)d_in[3];
  const float* b_in    = (const float*)d_in[4];
  const float* w_hid   = (const float*)d_in[5];
  const float* b_hid   = (const float*)d_in[6];
  const float* w_out   = (const float*)d_in[7];
  const float* b_out   = (const float*)d_in[8];
  const int n = in_sizes[0] / BATCH;

  u16* wsu = (u16*)d_ws;
  float* wsf = (float*)((char*)d_ws + (size_t)WS_USH * 2);
  float* out = (float*)d_out;
  const size_t xe = (size_t)BATCH * (n + 1);
  float* Xo  = out;
  float* eP  = out + xe;
  float* Xc  = out + xe + 1;
  float* ecP = out + 2 * xe + 1;

  const int prepBlocks = (PREP_TOTAL + 255) / 256;
  prep_kernel<<<prepBlocks, 256, 0, stream>>>(w_in, b_in, w_hid, b_hid, w_out, b_out,
                                              variant, n, wsu, wsf);
  if (n == 16)
    fused_kernel<16><<<NBLK, 512, 0, stream>>>(T, wsu, wsf, Xo, Xc, wsf + PART_F, n);
  else
    fused_kernel<0><<<NBLK, 512, 0, stream>>>(T, wsu, wsf, Xo, Xc, wsf + PART_F, n);
  finalize_kernel<<<1, 256, 0, stream>>>(wsf + PART_F, eP, ecP, 1.f / (float)((size_t)BATCH * n));
}

// Round 10
// 134.837 us; speedup vs baseline: 1.7525x; 1.1296x over previous
//
#include <hip/hip_runtime.h>

#define BATCH 65536
#define MT 64                 // rows per block
#define NBLK (BATCH / MT)     // 1024

typedef unsigned short u16;
typedef __bf16 bf16x8 __attribute__((ext_vector_type(8)));
typedef float f32x4 __attribute__((ext_vector_type(4)));

// d_ws layout (u16 element offsets)
// WI/WH tiles: [K32-tile][g(0..3)][col(0..511)][e(0..7)]  -> 16384 u16 = 32KB per K32 tile
//   element (col, k=K32*32+g*8+e) at tile + g*4096 + col*8 + e  (linear stage, stride-1 reads)
// WO keeps fragment layout [K32][col(32)][g][e] (read direct from global)
#define WI_OFF 0              // 1 tile   (k>=16 zero)
#define WH_OFF 16384          // 32 tiles (2 layers x 16)
#define WO_OFF 540672
#define WS_USH 557056
// float region at (char*)ws + WS_USH*2
#define BI_F 0
#define BH_F 512
#define BO_F 1536
#define PART_F 1568           // [NBLK][2] per-block error partials
#define PREP_WH 65536
#define PREP_WI 2048
#define PREP_WO 2048
#define PREP_SC 1568
#define PREP_TOTAL (PREP_WH + PREP_WI + PREP_WO + PREP_SC)

__device__ inline u16 f2bf(float f) {
  union { float f; unsigned u; } v; v.f = f;
  unsigned u = v.u + 0x7fffu + ((v.u >> 16) & 1u);   // RNE
  return (u16)(u >> 16);
}

__global__ void prep_kernel(const float* __restrict__ w_in, const float* __restrict__ b_in,
                            const float* __restrict__ w_hid, const float* __restrict__ b_hid,
                            const float* __restrict__ w_out, const float* __restrict__ b_out,
                            const int* __restrict__ variant, int n,
                            u16* __restrict__ wsu, float* __restrict__ wsf)
{
  const int model = (n - 5) * 16 + variant[0];
  const int i = blockIdx.x * 256 + threadIdx.x;
  if (i < PREP_WH) {
    // i = ((l*16 + K32)*4 + g)*512 + col ; dst 8 consecutive elems
    int col = i & 511, g = (i >> 9) & 3, K32 = (i >> 11) & 15, l = i >> 15;
    const float* src = w_hid + (size_t)model * 524288 + (size_t)l * 262144 + col * 512 + K32 * 32 + g * 8;
    u16* dst = wsu + WH_OFF + (size_t)i * 8;
    #pragma unroll
    for (int e = 0; e < 8; ++e) dst[e] = f2bf(src[e]);
  } else if (i < PREP_WH + PREP_WI) {
    int j = i - PREP_WH;
    int col = j & 511, g = (j >> 9) & 3;
    u16* dst = wsu + WI_OFF + (size_t)j * 8;
    #pragma unroll
    for (int e = 0; e < 8; ++e) {
      int k = g * 8 + e;
      dst[e] = (k < 16) ? f2bf(w_in[(size_t)model * 8192 + col * 16 + k]) : (u16)0;
    }
  } else if (i < PREP_WH + PREP_WI + PREP_WO) {
    int j = i - PREP_WH - PREP_WI;
    int g = j & 3, col = (j >> 2) & 31, K32 = j >> 7;
    u16* dst = wsu + WO_OFF + (size_t)j * 8;
    #pragma unroll
    for (int e = 0; e < 8; ++e) {
      int k = K32 * 32 + g * 8 + e;
      dst[e] = (col < 17) ? f2bf(w_out[(size_t)model * 8704 + col * 512 + k]) : (u16)0;
    }
  } else if (i < PREP_TOTAL) {
    int j = i - PREP_WH - PREP_WI - PREP_WO;
    if (j < 512)       wsf[BI_F + j] = b_in[(size_t)model * 512 + j];
    else if (j < 1536) wsf[BH_F + (j - 512)] = b_hid[(size_t)model * 1024 + (j - 512)];
    else               { int o = j - 1536; wsf[BO_F + o] = (o < 17) ? b_out[(size_t)model * 17 + o] : 0.f; }
  }
}

// xs layout: byte = row*1024 + ((col*2) ^ ((row&15)<<4))  (2-way max on reads)
__device__ __forceinline__ bf16x8 rdA(const char* xb, int row, int kbyte) {
  return *reinterpret_cast<const bf16x8*>(xb + row * 1024 + (kbyte ^ ((row & 15) << 4)));
}
__device__ __forceinline__ void st16(char* xb, int row, int col, u16 v) {
  *(u16*)(xb + row * 1024 + ((col * 2) ^ ((row & 15) << 4))) = v;
}

// async global->LDS, 16B per lane; LDS dest must be wave-uniform base + lane*16 (it is:
// dest = bufbase + tid*16 + c*8192, lanes contiguous within wave).
__device__ __forceinline__ void stage16(const u16* g, const u16* l) {
  __builtin_amdgcn_global_load_lds(
      (const __attribute__((address_space(1))) u16*)(uintptr_t)g,
      (__attribute__((address_space(3))) u16*)(unsigned)(uintptr_t)l,
      16, 0, 0);
}

template<int CN>
__global__ __launch_bounds__(512, 2) void fused_kernel(
    const float* __restrict__ T, const u16* __restrict__ wsu,
    const float* __restrict__ wsf, float* __restrict__ Xout, float* __restrict__ Xcout,
    float* __restrict__ errPart, int n_arg)
{
  const int n = CN ? CN : n_arg;
  __shared__ u16 xs[MT * 512];       // 64 KiB activations, XOR-swizzled
  __shared__ u16 bs[2 * 16384];      // 64 KiB: 2 x 32KB B-tiles (double buffer)
  __shared__ float xo[MT * 20];      // 5 KiB X_hat rows
  __shared__ float ts[MT * 16];      // 4 KiB T rows
  __shared__ float scaleS[MT];
  __shared__ float ered[8][2];

  const int tid = threadIdx.x;
  const int blk = blockIdx.x;
  const int lane = tid & 63;
  const int wid = tid >> 6;          // 0..7
  const int l15 = lane & 15;
  const int q = lane >> 4;           // 0..3
  const int c0 = wid * 64;           // wave's column base (hidden layers)
  char* xb = (char*)xs;
  char* bsB = (char*)bs;

  // B-read byte offsets within a staged tile: [g=q][col][8e] -> stride-1, conflict-free
  int bofs[4];
  #pragma unroll
  for (int ct = 0; ct < 4; ++ct)
    bofs[ct] = q * 8192 + (c0 + ct * 16 + l15) * 16;

  // stage tile tau (0=WI, 1..16=L1 steps, 17..32=L2 steps) into bs buf (tau&1)
  auto stageTile = [&](int tau) {
    if (tau > 32) return;
    const u16* src = (tau == 0) ? (wsu + WI_OFF)
                   : (tau <= 16) ? (wsu + WH_OFF + (size_t)(tau - 1) * 16384)
                                 : (wsu + WH_OFF + 262144 + (size_t)(tau - 17) * 16384);
    char* dst = bsB + ((tau & 1) << 15);
    const char* s = (const char*)src;
    #pragma unroll
    for (int c = 0; c < 4; ++c) {
      int d = tid * 16 + c * 8192;
      stage16((const u16*)(s + d), (const u16*)(dst + d));
    }
  };

  f32x4 acc[4][4];
  #pragma unroll
  for (int a = 0; a < 4; ++a)
    #pragma unroll
    for (int b = 0; b < 4; ++b) { f32x4 z = {0.f, 0.f, 0.f, 0.f}; acc[a][b] = z; }

  auto computeTile = [&](int buf, int kbA) {
    const char* bb = bsB + (buf << 15);
    bf16x8 av[4];
    #pragma unroll
    for (int mt = 0; mt < 4; ++mt) av[mt] = rdA(xb, mt * 16 + l15, kbA);
    #pragma unroll
    for (int ct = 0; ct < 4; ++ct) {
      bf16x8 b = *reinterpret_cast<const bf16x8*>(bb + bofs[ct]);
      #pragma unroll
      for (int mt = 0; mt < 4; ++mt)
        acc[mt][ct] = __builtin_amdgcn_mfma_f32_16x16x32_bf16(av[mt], b, acc[mt][ct], 0, 0, 0);
    }
  };

  auto epilogue = [&](const float* bias, int act) {
    float bv[4];
    #pragma unroll
    for (int ct = 0; ct < 4; ++ct) bv[ct] = bias[c0 + ct * 16 + l15];
    #pragma unroll
    for (int mt = 0; mt < 4; ++mt)
      #pragma unroll
      for (int ct = 0; ct < 4; ++ct) {
        #pragma unroll
        for (int j = 0; j < 4; ++j) {
          int row = mt * 16 + q * 4 + j;
          float z = acc[mt][ct][j] + bv[ct];
          float h = act ? fmaxf(z, 0.f) : z / (1.f + __expf(-z));
          st16(xb, row, c0 + ct * 16 + l15, f2bf(h));
        }
        f32x4 zz = {0.f, 0.f, 0.f, 0.f};
        acc[mt][ct] = zz;
      }
  };

  // ---- issue first two B-tiles immediately (latency hides under T prologue) ----
  stageTile(0);
  stageTile(1);

  // ---- prologue: T load + normalize; 8 threads/row ----
  {
    const int r = tid >> 3, j = tid & 7;
    const size_t gr = (size_t)blk * MT + r;
    const float* tp = T + gr * n;
    const int k0 = 2 * j, k1 = 2 * j + 1;
    float v0 = (k0 < n) ? tp[k0] : 0.f;
    float v1 = (k1 < n) ? tp[k1] : 0.f;
    float ss = v0 * v0 + v1 * v1;
    ss += __shfl_xor(ss, 1); ss += __shfl_xor(ss, 2); ss += __shfl_xor(ss, 4);
    float norm = sqrtf(ss < 1e-12f ? 1e-12f : ss);
    float rn = 1.f / norm;
    if (j == 0) scaleS[r] = sqrtf(norm);
    st16(xb, r, k0, f2bf(v0 * rn));
    st16(xb, r, k1, f2bf(v1 * rn));
    st16(xb, r, 16 + k0, 0);
    st16(xb, r, 16 + k1, 0);
    ts[r * 16 + k0] = v0;
    ts[r * 16 + k1] = v1;
  }

  // ---- L0 (WI, tile 0): one K=32 step ----
  asm volatile("s_waitcnt vmcnt(4) lgkmcnt(0)" ::: "memory");
  __builtin_amdgcn_s_barrier();
  computeTile(0, q * 16);
  __builtin_amdgcn_s_barrier();
  stageTile(2);
  epilogue(wsf + BI_F, 0);
  asm volatile("s_waitcnt lgkmcnt(0)" ::: "memory");
  __builtin_amdgcn_s_barrier();

  // ---- L1 (tiles 1..16) ----
  #pragma unroll 1
  for (int i = 0; i < 16; ++i) {
    asm volatile("s_waitcnt vmcnt(4)" ::: "memory");
    __builtin_amdgcn_s_barrier();
    computeTile((1 + i) & 1, i * 64 + q * 16);
    __builtin_amdgcn_s_barrier();
    stageTile(3 + i);                       // tiles 3..18 (incl. L2 steps 0,1)
  }
  epilogue(wsf + BH_F, 1);
  asm volatile("s_waitcnt lgkmcnt(0)" ::: "memory");
  __builtin_amdgcn_s_barrier();

  // ---- L2 (tiles 17..32) ----
  #pragma unroll 1
  for (int i = 0; i < 15; ++i) {
    asm volatile("s_waitcnt vmcnt(4)" ::: "memory");
    __builtin_amdgcn_s_barrier();
    computeTile((17 + i) & 1, i * 64 + q * 16);
    __builtin_amdgcn_s_barrier();
    stageTile(19 + i);                      // tiles 19..33 (33 skipped)
  }
  // peeled last step: only tile 32's 4 loads outstanding
  asm volatile("s_waitcnt vmcnt(0)" ::: "memory");
  __builtin_amdgcn_s_barrier();
  computeTile(0, 15 * 64 + q * 16);         // tile 32 -> buf 0
  __builtin_amdgcn_s_barrier();
  epilogue(wsf + BH_F + 512, 1);
  asm volatile("s_waitcnt lgkmcnt(0)" ::: "memory");
  __builtin_amdgcn_s_barrier();

  // ---- output layer: 8 waves; wave w -> rows (w>>1)*16..+16, col-half (w&1) ----
  {
    const int rg = wid >> 1;
    const int ch = wid & 1;
    f32x4 oacc = {0.f, 0.f, 0.f, 0.f};
    const u16* WoL = wsu + WO_OFF + (ch * 16 + l15) * 32 + q * 8;
    uint4 ob = *reinterpret_cast<const uint4*>(WoL);
    #pragma unroll 1
    for (int K = 0; K < 16; K += 2) {
      uint4 on = *reinterpret_cast<const uint4*>(WoL + (size_t)(K + 1) * 1024);
      {
        bf16x8 a0 = rdA(xb, rg * 16 + l15, K * 64 + q * 16);
        oacc = __builtin_amdgcn_mfma_f32_16x16x32_bf16(a0, __builtin_bit_cast(bf16x8, ob), oacc, 0, 0, 0);
      }
      ob = *reinterpret_cast<const uint4*>(WoL + (size_t)((K + 2) & 15) * 1024);
      {
        bf16x8 a1 = rdA(xb, rg * 16 + l15, (K + 1) * 64 + q * 16);
        oacc = __builtin_amdgcn_mfma_f32_16x16x32_bf16(a1, __builtin_bit_cast(bf16x8, on), oacc, 0, 0, 0);
      }
    }
    const int o = ch * 16 + l15;
    #pragma unroll
    for (int j = 0; j < 4; ++j) {
      int row = rg * 16 + q * 4 + j;
      if (o <= n) {
        float val = (oacc[j] + wsf[BO_F + o]) * scaleS[row];
        size_t gr = (size_t)blk * MT + row;
        float cv = fminf(fmaxf(val, -2.f), 2.f);
        Xout[gr * (n + 1) + o] = val;
        Xcout[gr * (n + 1) + o] = cv;
        xo[row * 20 + o] = val;
      }
    }
  }
  __syncthreads();

  // ---- distortion + squared-error partials: 8 threads/row, T from LDS ----
  {
    const int r = tid >> 3, j = tid & 7;
    float x[17], cx[17];
    #pragma unroll
    for (int i = 0; i < 17; ++i) {
      float v = (i <= n) ? xo[r * 20 + i] : 0.f;
      x[i] = v; cx[i] = fminf(fmaxf(v, -2.f), 2.f);
    }
    float e = 0.f, ec = 0.f;
    #pragma unroll
    for (int kk = 0; kk < 2; ++kk) {
      int k = j + 1 + kk * 8;
      if (k <= n) {
        float d = 0.f, dc = 0.f;
        #pragma unroll
        for (int i = 0; i < 16; ++i) {
          if (i + k <= 16) {
            if (i + k <= n) { d += x[i] * x[i + k]; dc += cx[i] * cx[i + k]; }
          }
        }
        float tvv = ts[r * 16 + (n - k)];
        float r1 = d - tvv, r2 = dc - tvv;
        e += r1 * r1; ec += r2 * r2;
      }
    }
    e += __shfl_xor(e, 1);  ec += __shfl_xor(ec, 1);
    e += __shfl_xor(e, 2);  ec += __shfl_xor(ec, 2);
    e += __shfl_xor(e, 4);  ec += __shfl_xor(ec, 4);
    e += __shfl_xor(e, 8);  ec += __shfl_xor(ec, 8);
    e += __shfl_xor(e, 16); ec += __shfl_xor(ec, 16);
    e += __shfl_xor(e, 32); ec += __shfl_xor(ec, 32);
    if (lane == 0) { ered[wid][0] = e; ered[wid][1] = ec; }
  }
  __syncthreads();
  if (tid == 0) {
    float e = 0.f, ec = 0.f;
    #pragma unroll
    for (int w = 0; w < 8; ++w) { e += ered[w][0]; ec += ered[w][1]; }
    errPart[blk * 2]     = e;
    errPart[blk * 2 + 1] = ec;
  }
}

__global__ void finalize_kernel(const float* __restrict__ part, float* __restrict__ e0,
                                float* __restrict__ e1, float inv)
{
  __shared__ float se[4][2];
  const int t = threadIdx.x;           // 256 threads
  float e = 0.f, ec = 0.f;
  for (int b = t; b < NBLK; b += 256) { e += part[2 * b]; ec += part[2 * b + 1]; }
  e += __shfl_xor(e, 1);  ec += __shfl_xor(ec, 1);
  e += __shfl_xor(e, 2);  ec += __shfl_xor(ec, 2);
  e += __shfl_xor(e, 4);  ec += __shfl_xor(ec, 4);
  e += __shfl_xor(e, 8);  ec += __shfl_xor(ec, 8);
  e += __shfl_xor(e, 16); ec += __shfl_xor(ec, 16);
  e += __shfl_xor(e, 32); ec += __shfl_xor(ec, 32);
  if ((t & 63) == 0) { se[t >> 6][0] = e; se[t >> 6][1] = ec; }
  __syncthreads();
  if (t == 0) {
    float te = 0.f, tec = 0.f;
    #pragma unroll
    for (int w = 0; w < 4; ++w) { te += se[w][0]; tec += se[w][1]; }
    e0[0] = te * inv;
    e1[0] = tec * inv;
  }
}

extern "C" void kernel_launch(void* const* d_in, const int* in_sizes, int n_in,
                              void* d_out, int out_size, void* d_ws, size_t ws_size,
                              hipStream_t stream)
{
  const float* T       = (const float*)d_in[0];
  const int*   variant = (const int*)d_in[2];
  const float* w_in    = (const float*)d_in[3];
  const float* b_in    = (const float*)d_in[4];
  const float* w_hid   = (const float*)d_in[5];
  const float* b_hid   = (const float*)d_in[6];
  const float* w_out   = (const float*)d_in[7];
  const float* b_out   = (const float*)d_in[8];
  const int n = in_sizes[0] / BATCH;

  u16* wsu = (u16*)d_ws;
  float* wsf = (float*)((char*)d_ws + (size_t)WS_USH * 2);
  float* out = (float*)d_out;
  const size_t xe = (size_t)BATCH * (n + 1);
  float* Xo  = out;
  float* eP  = out + xe;
  float* Xc  = out + xe + 1;
  float* ecP = out + 2 * xe + 1;

  const int prepBlocks = (PREP_TOTAL + 255) / 256;
  prep_kernel<<<prepBlocks, 256, 0, stream>>>(w_in, b_in, w_hid, b_hid, w_out, b_out,
                                              variant, n, wsu, wsf);
  if (n == 16)
    fused_kernel<16><<<NBLK, 512, 0, stream>>>(T, wsu, wsf, Xo, Xc, wsf + PART_F, n);
  else
    fused_kernel<0><<<NBLK, 512, 0, stream>>>(T, wsu, wsf, Xo, Xc, wsf + PART_F, n);
  finalize_kernel<<<1, 256, 0, stream>>>(wsf + PART_F, eP, ecP, 1.f / (float)((size_t)BATCH * n));
}